// Round 1
// baseline (298.049 us; speedup 1.0000x reference)
//
#include <hip/hip_runtime.h>
#include <math.h>

#define NCLS 1000
#define NV4  250        // 1000 floats = 250 float4 per row (4000 B, 16B-aligned)
#define INV_TEMP 0.5f   // 1/TEMPERATURE

// One wave (64 lanes) per row. 4 waves per 256-thread block.
__global__ __launch_bounds__(256) void margins_kernel(
    const float* __restrict__ o1, const float* __restrict__ o2,
    const float* __restrict__ o3, const float* __restrict__ o4,
    const float* __restrict__ mim, const int* __restrict__ targets,
    float* __restrict__ out, float* __restrict__ blockmax, int n)
{
    const int lane = threadIdx.x & 63;
    const int wid  = threadIdx.x >> 6;
    const int row  = blockIdx.x * 4 + wid;
    __shared__ float smax[4];

    float gm = -INFINITY;           // running max over outputs1..4 (this wave's slice)
    const float* mats[5] = {o1, o2, o3, o4, mim};

    float preds[5];

    if (row < n) {
        const int tgt = targets[row];
        #pragma unroll
        for (int m = 0; m < 5; ++m) {
            const float*  rowp = mats[m] + (size_t)row * NCLS;
            const float4* p4   = (const float4*)rowp;
            float m1 = -INFINITY, m2 = -INFINITY;
            #pragma unroll
            for (int it = 0; it < 4; ++it) {
                const int idx = lane + it * 64;
                if (idx < NV4) {
                    float4 v = p4[idx];
                    // branchless top-2 update (min uses OLD m1)
                    m2 = fmaxf(m2, fminf(m1, v.x)); m1 = fmaxf(m1, v.x);
                    m2 = fmaxf(m2, fminf(m1, v.y)); m1 = fmaxf(m1, v.y);
                    m2 = fmaxf(m2, fminf(m1, v.z)); m1 = fmaxf(m1, v.z);
                    m2 = fmaxf(m2, fminf(m1, v.w)); m1 = fmaxf(m1, v.w);
                    if (m < 4) {  // global max excludes mimic
                        gm = fmaxf(gm, fmaxf(fmaxf(v.x, v.y), fmaxf(v.z, v.w)));
                    }
                }
            }
            // wave-wide top-2 butterfly merge (64 lanes)
            #pragma unroll
            for (int off = 32; off > 0; off >>= 1) {
                float q1 = __shfl_xor(m1, off, 64);
                float q2 = __shfl_xor(m2, off, 64);
                m2 = fmaxf(fmaxf(m2, q2), fminf(m1, q1));
                m1 = fmaxf(m1, q1);
            }
            // target value: broadcast load (all lanes same addr -> 1 txn, L1/L2-hot)
            const float tv = rowp[tgt];
            preds[m] = (m1 == tv) ? (m1 - m2) : 0.0f;
        }

        // softmax over 5 margins at temperature 2 (redundant across lanes; cheap)
        const float p0 = preds[0] * INV_TEMP, p1 = preds[1] * INV_TEMP,
                    p2 = preds[2] * INV_TEMP, p3 = preds[3] * INV_TEMP,
                    p4 = preds[4] * INV_TEMP;
        const float pm = fmaxf(fmaxf(fmaxf(p0, p1), fmaxf(p2, p3)), p4);
        const float e0 = expf(p0 - pm), e1 = expf(p1 - pm), e2 = expf(p2 - pm),
                    e3 = expf(p3 - pm), e4 = expf(p4 - pm);
        const float inv = 1.0f / (e0 + e1 + e2 + e3 + e4);
        if (lane == 0) {
            float* b = out + 1 + (size_t)row * 5;   // out[0] is max_preds (kernel 2)
            b[0] = e0 * inv; b[1] = e1 * inv; b[2] = e2 * inv;
            b[3] = e3 * inv; b[4] = e4 * inv;
        }
    }

    // wave-reduce global max, then block-reduce via LDS
    #pragma unroll
    for (int off = 32; off > 0; off >>= 1)
        gm = fmaxf(gm, __shfl_xor(gm, off, 64));
    if (lane == 0) smax[wid] = gm;
    __syncthreads();
    if (threadIdx.x == 0) {
        blockmax[blockIdx.x] =
            fmaxf(fmaxf(smax[0], smax[1]), fmaxf(smax[2], smax[3]));
    }
}

__global__ __launch_bounds__(256) void final_max_kernel(
    const float* __restrict__ blockmax, int nblocks, float* __restrict__ out)
{
    float m = -INFINITY;
    for (int i = threadIdx.x; i < nblocks; i += 256) m = fmaxf(m, blockmax[i]);
    #pragma unroll
    for (int off = 32; off > 0; off >>= 1)
        m = fmaxf(m, __shfl_xor(m, off, 64));
    __shared__ float s[4];
    const int lane = threadIdx.x & 63, wid = threadIdx.x >> 6;
    if (lane == 0) s[wid] = m;
    __syncthreads();
    if (threadIdx.x == 0)
        out[0] = fmaxf(fmaxf(s[0], s[1]), fmaxf(s[2], s[3]));
}

extern "C" void kernel_launch(void* const* d_in, const int* in_sizes, int n_in,
                              void* d_out, int out_size, void* d_ws, size_t ws_size,
                              hipStream_t stream) {
    const float* o1  = (const float*)d_in[0];
    const float* o2  = (const float*)d_in[1];
    const float* o3  = (const float*)d_in[2];
    const float* o4  = (const float*)d_in[3];
    const float* mim = (const float*)d_in[4];
    const int*   tgt = (const int*)d_in[5];
    const int n = in_sizes[5];            // 16384 rows

    float* out = (float*)d_out;
    float* ws  = (float*)d_ws;            // one float per block

    const int blocks = (n + 3) / 4;       // 4 rows (waves) per block
    margins_kernel<<<blocks, 256, 0, stream>>>(o1, o2, o3, o4, mim, tgt, out, ws, n);
    final_max_kernel<<<1, 256, 0, stream>>>(ws, blocks, out);
}

// Round 2
// 295.013 us; speedup vs baseline: 1.0103x; 1.0103x over previous
//
#include <hip/hip_runtime.h>
#include <math.h>

#define NCLS 1000
#define NV4  250        // 1000 floats = 250 float4 per row (4000 B, 16B-aligned)
#define INV_TEMP 0.5f   // 1/TEMPERATURE
#define NEG_INF (-INFINITY)

// One wave (64 lanes) per row. 4 waves per 256-thread block.
// All 20 row loads (5 mats x 4 float4) issued before any use -> high MLP.
__global__ __launch_bounds__(256, 4) void margins_kernel(
    const float* __restrict__ o1, const float* __restrict__ o2,
    const float* __restrict__ o3, const float* __restrict__ o4,
    const float* __restrict__ mim, const int* __restrict__ targets,
    float* __restrict__ out, float* __restrict__ blockmax, int n)
{
    const int lane = threadIdx.x & 63;
    const int wid  = threadIdx.x >> 6;
    const int row  = blockIdx.x * 4 + wid;
    __shared__ float smax[4];

    float gm = NEG_INF;             // running max over outputs1..4
    const float* mats[5] = {o1, o2, o3, o4, mim};

    if (row < n) {
        const int tgt = targets[row];
        const float4* p4[5];
        #pragma unroll
        for (int m = 0; m < 5; ++m)
            p4[m] = (const float4*)(mats[m] + (size_t)row * NCLS);

        // ---- issue ALL loads up front (20 independent 16B loads/lane) ----
        float4 v[5][4];
        #pragma unroll
        for (int it = 0; it < 3; ++it) {
            const int idx = lane + it * 64;
            #pragma unroll
            for (int m = 0; m < 5; ++m) v[m][it] = p4[m][idx];
        }
        {   // iteration 3: clamp index (no predication on the load itself)
            const int idx = 192 + lane;
            const int idc = (idx < NV4) ? idx : (NV4 - 1);
            #pragma unroll
            for (int m = 0; m < 5; ++m) v[m][3] = p4[m][idc];
        }
        // target values: wave-uniform broadcast loads (L1/L2-hot)
        float tv[5];
        #pragma unroll
        for (int m = 0; m < 5; ++m) tv[m] = ((const float*)p4[m])[tgt];

        // neutralize tail lanes (idx 250..255) with -inf
        if (192 + lane >= NV4) {
            #pragma unroll
            for (int m = 0; m < 5; ++m)
                v[m][3] = make_float4(NEG_INF, NEG_INF, NEG_INF, NEG_INF);
        }

        // ---- consume: per-lane top-2 (tree form), then wave butterfly ----
        float preds[5];
        #pragma unroll
        for (int m = 0; m < 5; ++m) {
            float m1 = NEG_INF, m2 = NEG_INF;
            #pragma unroll
            for (int it = 0; it < 4; ++it) {
                const float4 vv = v[m][it];
                const float hi1 = fmaxf(vv.x, vv.y), lo1 = fminf(vv.x, vv.y);
                const float hi2 = fmaxf(vv.z, vv.w), lo2 = fminf(vv.z, vv.w);
                const float t1  = fmaxf(hi1, hi2);
                const float t2  = fmaxf(fminf(hi1, hi2), fmaxf(lo1, lo2));
                m2 = fmaxf(fmaxf(m2, t2), fminf(m1, t1));
                m1 = fmaxf(m1, t1);
                if (m < 4) gm = fmaxf(gm, t1);
            }
            #pragma unroll
            for (int off = 32; off > 0; off >>= 1) {
                const float q1 = __shfl_xor(m1, off, 64);
                const float q2 = __shfl_xor(m2, off, 64);
                m2 = fmaxf(fmaxf(m2, q2), fminf(m1, q1));
                m1 = fmaxf(m1, q1);
            }
            preds[m] = (m1 == tv[m]) ? (m1 - m2) : 0.0f;
        }

        // softmax over 5 margins at temperature 2 (redundant per lane; cheap)
        const float p0 = preds[0] * INV_TEMP, p1 = preds[1] * INV_TEMP,
                    p2 = preds[2] * INV_TEMP, p3 = preds[3] * INV_TEMP,
                    p4v = preds[4] * INV_TEMP;
        const float pm = fmaxf(fmaxf(fmaxf(p0, p1), fmaxf(p2, p3)), p4v);
        const float e0 = expf(p0 - pm), e1 = expf(p1 - pm), e2 = expf(p2 - pm),
                    e3 = expf(p3 - pm), e4 = expf(p4v - pm);
        const float inv = 1.0f / (e0 + e1 + e2 + e3 + e4);
        if (lane == 0) {
            float* b = out + 1 + (size_t)row * 5;   // out[0] is max_preds
            b[0] = e0 * inv; b[1] = e1 * inv; b[2] = e2 * inv;
            b[3] = e3 * inv; b[4] = e4 * inv;
        }
    }

    // wave-reduce global max, then block-reduce via LDS
    #pragma unroll
    for (int off = 32; off > 0; off >>= 1)
        gm = fmaxf(gm, __shfl_xor(gm, off, 64));
    if (lane == 0) smax[wid] = gm;
    __syncthreads();
    if (threadIdx.x == 0) {
        blockmax[blockIdx.x] =
            fmaxf(fmaxf(smax[0], smax[1]), fmaxf(smax[2], smax[3]));
    }
}

__global__ __launch_bounds__(256) void final_max_kernel(
    const float* __restrict__ blockmax, int nblocks, float* __restrict__ out)
{
    float m = NEG_INF;
    for (int i = threadIdx.x; i < nblocks; i += 256) m = fmaxf(m, blockmax[i]);
    #pragma unroll
    for (int off = 32; off > 0; off >>= 1)
        m = fmaxf(m, __shfl_xor(m, off, 64));
    __shared__ float s[4];
    const int lane = threadIdx.x & 63, wid = threadIdx.x >> 6;
    if (lane == 0) s[wid] = m;
    __syncthreads();
    if (threadIdx.x == 0)
        out[0] = fmaxf(fmaxf(s[0], s[1]), fmaxf(s[2], s[3]));
}

extern "C" void kernel_launch(void* const* d_in, const int* in_sizes, int n_in,
                              void* d_out, int out_size, void* d_ws, size_t ws_size,
                              hipStream_t stream) {
    const float* o1  = (const float*)d_in[0];
    const float* o2  = (const float*)d_in[1];
    const float* o3  = (const float*)d_in[2];
    const float* o4  = (const float*)d_in[3];
    const float* mim = (const float*)d_in[4];
    const int*   tgt = (const int*)d_in[5];
    const int n = in_sizes[5];            // 16384 rows

    float* out = (float*)d_out;
    float* ws  = (float*)d_ws;            // one float per block

    const int blocks = (n + 3) / 4;       // 4 rows (waves) per block
    margins_kernel<<<blocks, 256, 0, stream>>>(o1, o2, o3, o4, mim, tgt, out, ws, n);
    final_max_kernel<<<1, 256, 0, stream>>>(ws, blocks, out);
}

// Round 3
// 294.804 us; speedup vs baseline: 1.0110x; 1.0007x over previous
//
#include <hip/hip_runtime.h>
#include <math.h>

#define NCLS 1000
#define NV4  250        // 1000 floats = 250 float4 per row
#define INV_TEMP 0.5f   // 1/TEMPERATURE
#define NEG_INF (-INFINITY)

// merge two ordered top-2 pairs: (a1>=a2) U (b1>=b2) -> top-2 in (a1,a2)
__device__ __forceinline__ void merge2(float& a1, float& a2, float b1, float b2) {
    const float mn = fminf(a1, b1);
    a1 = fmaxf(a1, b1);
    a2 = fmaxf(mn, fmaxf(a2, b2));
}

// 16 lanes per row; 4 rows per wave; 4 waves (16 rows) per 256-thread block.
// Cross-lane butterfly: 4 steps x 5 matrices interleaved (vs 6 steps x 5 serial).
__global__ __launch_bounds__(256, 3) void margins_kernel(
    const float* __restrict__ o1, const float* __restrict__ o2,
    const float* __restrict__ o3, const float* __restrict__ o4,
    const float* __restrict__ mim, const int* __restrict__ targets,
    float* __restrict__ out, float* __restrict__ blockmax, int n)
{
    const int lane = threadIdx.x & 63;
    const int wid  = threadIdx.x >> 6;
    const int grp  = lane >> 4;      // 4 row-groups per wave
    const int sub  = lane & 15;      // position within the 16-lane group
    const int row  = blockIdx.x * 16 + wid * 4 + grp;
    __shared__ float smax[4];

    float gm = NEG_INF;              // running max over outputs1..4
    const float* mats[5] = {o1, o2, o3, o4, mim};

    if (row < n) {
        const int tgt = targets[row];

        // target values first (wave-4-address broadcast loads, L1/L2-hot later)
        float tv[5];
        #pragma unroll
        for (int m = 0; m < 5; ++m)
            tv[m] = (mats[m] + (size_t)row * NCLS)[tgt];

        float m1g[5], m2g[5];
        #pragma unroll
        for (int m = 0; m < 5; ++m) {
            const float4* p4 = (const float4*)(mats[m] + (size_t)row * NCLS);
            // 16 float4 per lane; group covers 256B-contiguous segments
            float4 v[16];
            #pragma unroll
            for (int it = 0; it < 15; ++it) v[it] = p4[it * 16 + sub];
            v[15] = p4[(sub < 10) ? (240 + sub) : 249];
            if (sub >= 10)
                v[15] = make_float4(NEG_INF, NEG_INF, NEG_INF, NEG_INF);

            // per-float4 top-2, then depth-4 pairwise merge tree (ILP)
            float t1[16], t2[16];
            #pragma unroll
            for (int it = 0; it < 16; ++it) {
                const float hi1 = fmaxf(v[it].x, v[it].y), lo1 = fminf(v[it].x, v[it].y);
                const float hi2 = fmaxf(v[it].z, v[it].w), lo2 = fminf(v[it].z, v[it].w);
                t1[it] = fmaxf(hi1, hi2);
                t2[it] = fmaxf(fminf(hi1, hi2), fmaxf(lo1, lo2));
            }
            #pragma unroll
            for (int s = 8; s >= 1; s >>= 1)
                #pragma unroll
                for (int i = 0; i < s; ++i)
                    merge2(t1[i], t2[i], t1[i + s], t2[i + s]);

            m1g[m] = t1[0];
            m2g[m] = t2[0];
            if (m < 4) gm = fmaxf(gm, t1[0]);
        }

        // cross-lane top-2 butterfly within 16-lane group; 5 independent
        // chains interleaved so DS latency pipelines
        #pragma unroll
        for (int off = 8; off >= 1; off >>= 1) {
            float q1[5], q2[5];
            #pragma unroll
            for (int m = 0; m < 5; ++m) {
                q1[m] = __shfl_xor(m1g[m], off, 64);
                q2[m] = __shfl_xor(m2g[m], off, 64);
            }
            #pragma unroll
            for (int m = 0; m < 5; ++m)
                merge2(m1g[m], m2g[m], q1[m], q2[m]);
        }

        float preds[5];
        #pragma unroll
        for (int m = 0; m < 5; ++m)
            preds[m] = (m1g[m] == tv[m]) ? (m1g[m] - m2g[m]) : 0.0f;

        // softmax over 5 margins at temperature 2
        const float p0 = preds[0] * INV_TEMP, p1 = preds[1] * INV_TEMP,
                    p2 = preds[2] * INV_TEMP, p3 = preds[3] * INV_TEMP,
                    p4v = preds[4] * INV_TEMP;
        const float pm = fmaxf(fmaxf(fmaxf(p0, p1), fmaxf(p2, p3)), p4v);
        const float e0 = expf(p0 - pm), e1 = expf(p1 - pm), e2 = expf(p2 - pm),
                    e3 = expf(p3 - pm), e4 = expf(p4v - pm);
        const float inv = 1.0f / (e0 + e1 + e2 + e3 + e4);
        if (sub == 0) {
            float* b = out + 1 + (size_t)row * 5;   // out[0] is max_preds
            b[0] = e0 * inv; b[1] = e1 * inv; b[2] = e2 * inv;
            b[3] = e3 * inv; b[4] = e4 * inv;
        }
    }

    // full-wave max reduce for gm, then block reduce via LDS
    #pragma unroll
    for (int off = 32; off > 0; off >>= 1)
        gm = fmaxf(gm, __shfl_xor(gm, off, 64));
    if (lane == 0) smax[wid] = gm;
    __syncthreads();
    if (threadIdx.x == 0) {
        blockmax[blockIdx.x] =
            fmaxf(fmaxf(smax[0], smax[1]), fmaxf(smax[2], smax[3]));
    }
}

__global__ __launch_bounds__(256) void final_max_kernel(
    const float* __restrict__ blockmax, int nblocks, float* __restrict__ out)
{
    float m = NEG_INF;
    for (int i = threadIdx.x; i < nblocks; i += 256) m = fmaxf(m, blockmax[i]);
    #pragma unroll
    for (int off = 32; off > 0; off >>= 1)
        m = fmaxf(m, __shfl_xor(m, off, 64));
    __shared__ float s[4];
    const int lane = threadIdx.x & 63, wid = threadIdx.x >> 6;
    if (lane == 0) s[wid] = m;
    __syncthreads();
    if (threadIdx.x == 0)
        out[0] = fmaxf(fmaxf(s[0], s[1]), fmaxf(s[2], s[3]));
}

extern "C" void kernel_launch(void* const* d_in, const int* in_sizes, int n_in,
                              void* d_out, int out_size, void* d_ws, size_t ws_size,
                              hipStream_t stream) {
    const float* o1  = (const float*)d_in[0];
    const float* o2  = (const float*)d_in[1];
    const float* o3  = (const float*)d_in[2];
    const float* o4  = (const float*)d_in[3];
    const float* mim = (const float*)d_in[4];
    const int*   tgt = (const int*)d_in[5];
    const int n = in_sizes[5];            // 16384 rows

    float* out = (float*)d_out;
    float* ws  = (float*)d_ws;            // one float per block

    const int blocks = (n + 15) / 16;     // 16 rows per block
    margins_kernel<<<blocks, 256, 0, stream>>>(o1, o2, o3, o4, mim, tgt, out, ws, n);
    final_max_kernel<<<1, 256, 0, stream>>>(ws, blocks, out);
}

// Round 4
// 293.531 us; speedup vs baseline: 1.0154x; 1.0043x over previous
//
#include <hip/hip_runtime.h>
#include <math.h>

#define NCLS  1000
#define NV4   250       // 1000 floats = 250 float4 per row
#define NROWS 16384
#define INV_TEMP 0.5f
#define NEG_INF (-INFINITY)

// merge two ordered top-2 pairs: (a1>=a2) U (b1>=b2) -> (a1,a2)
__device__ __forceinline__ void merge2(float& a1, float& a2, float b1, float b2) {
    const float mn = fminf(a1, b1);
    a1 = fmaxf(a1, b1);
    a2 = fmaxf(mn, fmaxf(a2, b2));
}

// One wave per (row, matrix) pair. 4 waves/block -> 20480 blocks of 81920
// short-lived waves: latency hidden by wave churn, not intra-wave pipelining.
// ws layout: [0, NROWS*5)              per-(row,mat) margins
//            [NROWS*5, +nblocks)       per-block max (mats 0..3 only)
//            [NROWS*5+nblocks, +64)    stage-2 partial maxes
__global__ __launch_bounds__(256) void margins_kernel(
    const float* __restrict__ o1, const float* __restrict__ o2,
    const float* __restrict__ o3, const float* __restrict__ o4,
    const float* __restrict__ mim, const int* __restrict__ targets,
    float* __restrict__ ws_margin, float* __restrict__ blockmax)
{
    const int lane = threadIdx.x & 63;
    const int wid  = threadIdx.x >> 6;
    const int pair = blockIdx.x * 4 + wid;     // < NROWS*5
    const int row  = pair / 5;                 // uniform per wave (magic mul)
    const int mat  = pair - row * 5;
    __shared__ float smax[4];

    const float* base = (mat == 0) ? o1 : (mat == 1) ? o2 : (mat == 2) ? o3
                      : (mat == 3) ? o4 : mim;
    const float*  rowp = base + (size_t)row * NCLS;
    const float4* p4   = (const float4*)rowp;

    // issue all memory up front: 4 independent dwordx4 + target gather
    const int tgt = targets[row];
    const float tv = rowp[tgt];
    float4 v0 = p4[lane];
    float4 v1 = p4[64  + lane];
    float4 v2 = p4[128 + lane];
    float4 v3 = p4[(lane < 58) ? (192 + lane) : 249];
    if (lane >= 58) v3 = make_float4(NEG_INF, NEG_INF, NEG_INF, NEG_INF);

    // per-float4 top-2, then depth-2 merge tree
    float t1[4], t2[4];
    const float4 vv[4] = {v0, v1, v2, v3};
    #pragma unroll
    for (int i = 0; i < 4; ++i) {
        const float hi1 = fmaxf(vv[i].x, vv[i].y), lo1 = fminf(vv[i].x, vv[i].y);
        const float hi2 = fmaxf(vv[i].z, vv[i].w), lo2 = fminf(vv[i].z, vv[i].w);
        t1[i] = fmaxf(hi1, hi2);
        t2[i] = fmaxf(fminf(hi1, hi2), fmaxf(lo1, lo2));
    }
    merge2(t1[0], t2[0], t1[1], t2[1]);
    merge2(t1[2], t2[2], t1[3], t2[3]);
    merge2(t1[0], t2[0], t1[2], t2[2]);
    float m1 = t1[0], m2 = t2[0];

    // 6-step wave butterfly -> wave-uniform top-2
    #pragma unroll
    for (int off = 32; off >= 1; off >>= 1) {
        const float q1 = __shfl_xor(m1, off, 64);
        const float q2 = __shfl_xor(m2, off, 64);
        merge2(m1, m2, q1, q2);
    }

    if (lane == 0) {
        ws_margin[pair] = (m1 == tv) ? (m1 - m2) : 0.0f;
        smax[wid] = (mat < 4) ? m1 : NEG_INF;   // row max, mats 0..3 only
    }
    __syncthreads();
    if (threadIdx.x == 0)
        blockmax[blockIdx.x] =
            fmaxf(fmaxf(smax[0], smax[1]), fmaxf(smax[2], smax[3]));
}

// One thread per row: softmax over 5 margins. Block b also reduces its
// 320-slice of blockmax into stage2[b].
__global__ __launch_bounds__(256) void softmax_kernel(
    const float* __restrict__ ws_margin, const float* __restrict__ blockmax,
    float* __restrict__ out, float* __restrict__ stage2, int nblocks)
{
    const int row = blockIdx.x * 256 + threadIdx.x;
    if (row < NROWS) {
        const float* pr = ws_margin + (size_t)row * 5;
        const float p0 = pr[0] * INV_TEMP, p1 = pr[1] * INV_TEMP,
                    p2 = pr[2] * INV_TEMP, p3 = pr[3] * INV_TEMP,
                    p4 = pr[4] * INV_TEMP;
        const float pm = fmaxf(fmaxf(fmaxf(p0, p1), fmaxf(p2, p3)), p4);
        const float e0 = expf(p0 - pm), e1 = expf(p1 - pm), e2 = expf(p2 - pm),
                    e3 = expf(p3 - pm), e4 = expf(p4 - pm);
        const float inv = 1.0f / (e0 + e1 + e2 + e3 + e4);
        float* b = out + 1 + (size_t)row * 5;
        b[0] = e0 * inv; b[1] = e1 * inv; b[2] = e2 * inv;
        b[3] = e3 * inv; b[4] = e4 * inv;
    }

    // reduce this block's slice of blockmax
    float m = NEG_INF;
    for (int i = blockIdx.x * 320 + threadIdx.x, e = min((int)((blockIdx.x + 1) * 320), nblocks);
         i < e; i += 256)
        m = fmaxf(m, blockmax[i]);
    #pragma unroll
    for (int off = 32; off >= 1; off >>= 1)
        m = fmaxf(m, __shfl_xor(m, off, 64));
    __shared__ float s[4];
    const int lane = threadIdx.x & 63, wid = threadIdx.x >> 6;
    if (lane == 0) s[wid] = m;
    __syncthreads();
    if (threadIdx.x == 0)
        stage2[blockIdx.x] = fmaxf(fmaxf(s[0], s[1]), fmaxf(s[2], s[3]));
}

__global__ __launch_bounds__(64) void final_max_kernel(
    const float* __restrict__ stage2, int n, float* __restrict__ out)
{
    float m = (threadIdx.x < n) ? stage2[threadIdx.x] : NEG_INF;
    #pragma unroll
    for (int off = 32; off >= 1; off >>= 1)
        m = fmaxf(m, __shfl_xor(m, off, 64));
    if (threadIdx.x == 0) out[0] = m;
}

extern "C" void kernel_launch(void* const* d_in, const int* in_sizes, int n_in,
                              void* d_out, int out_size, void* d_ws, size_t ws_size,
                              hipStream_t stream) {
    const float* o1  = (const float*)d_in[0];
    const float* o2  = (const float*)d_in[1];
    const float* o3  = (const float*)d_in[2];
    const float* o4  = (const float*)d_in[3];
    const float* mim = (const float*)d_in[4];
    const int*   tgt = (const int*)d_in[5];

    float* out = (float*)d_out;
    float* ws_margin = (float*)d_ws;                    // NROWS*5
    const int nblocks = (NROWS * 5) / 4;                // 20480
    float* blockmax = ws_margin + NROWS * 5;            // nblocks
    float* stage2   = blockmax + nblocks;               // 64

    margins_kernel<<<nblocks, 256, 0, stream>>>(o1, o2, o3, o4, mim, tgt,
                                                ws_margin, blockmax);
    softmax_kernel<<<64, 256, 0, stream>>>(ws_margin, blockmax, out, stage2, nblocks);
    final_max_kernel<<<1, 64, 0, stream>>>(stage2, 64, out);
}